// Round 9
// baseline (747.125 us; speedup 1.0000x reference)
//
#include <hip/hip_runtime.h>

#define N_NODES 100000
#define N_EDGES 1600000
#define D 64

// fine buckets: 32 nodes, 100000/32 = 3125 exactly
#define FSHIFT 5
#define FNODES 32
#define NFB 3125
#define CAPF 768            // mean 512, sigma ~22.6 -> +11.3 sigma

// coarse buckets: 2048 nodes
#define CSHIFT 11
#define NCB 49
#define CCAP 36864          // mean 32768, +22 sigma
#define FPC 64

#define CHUNKA 2048
#define EPTA 8
#define NCHUNKA 782
#define CHUNKB 2048
#define EPTB 8
#define NCHUNKB 18          // CCAP / 2048

#define COLBITS 17
#define COLMASK 0x1FFFF

// ws layout (bytes)
#define DEG_OFF    0           // int[100000]
#define CCUR_OFF   400000      // int[49]
#define FCUR_OFF   400256      // int[3125]
#define INIT_BYTES 412756      // one memset covers deg+ccur+fcur
#define DINV_OFF   413696      // float[100000]
#define Y_OFF      813696      // bf16[100000*64], node-major (16-aligned)
#define CPAIRS_OFF 13613696    // int[49*36864]
#define FPAIRS_OFF 20839040    // int[3125*768]

typedef float fvec4 __attribute__((ext_vector_type(4)));

__device__ __forceinline__ unsigned f2bf(float f) {
    unsigned bits = __float_as_uint(f);
    return (bits + 0x7FFFu + ((bits >> 16) & 1u)) >> 16;
}

// Pass A: bucket edges by row>>11 into 49 coarse regions + global degree count.
__global__ __launch_bounds__(256) void scatA_kernel(const int* __restrict__ row,
                                                    const int* __restrict__ col,
                                                    int* __restrict__ deg,
                                                    int* __restrict__ ccur,
                                                    int* __restrict__ cpairs) {
    __shared__ int lcnt[NCB];
    int t = threadIdx.x;
    int base = blockIdx.x * CHUNKA;
    if (t < NCB) lcnt[t] = 0;
    __syncthreads();
    int r[EPTA], c[EPTA], pos[EPTA];
#pragma unroll
    for (int i = 0; i < EPTA; ++i) {
        int e = base + i * 256 + t;
        if (e < N_EDGES) {
            r[i] = row[e];
            c[i] = col[e];
            pos[i] = atomicAdd(&lcnt[r[i] >> CSHIFT], 1);
            atomicAdd(&deg[r[i]], 1);
        } else r[i] = -1;
    }
    __syncthreads();
    if (t < NCB) {
        int cc = lcnt[t];
        if (cc) lcnt[t] = t * CCAP + atomicAdd(&ccur[t], cc);
    }
    __syncthreads();
#pragma unroll
    for (int i = 0; i < EPTA; ++i) {
        if (r[i] >= 0) {
            int cb = r[i] >> CSHIFT;
            int rl = r[i] & ((1 << CSHIFT) - 1);
            cpairs[lcnt[cb] + pos[i]] = (rl << COLBITS) | c[i];
        }
    }
}

// Pass B: refine one coarse chunk into its 64 fine buckets (32 nodes each).
__global__ __launch_bounds__(256) void scatB_kernel(const int* __restrict__ cpairs,
                                                    const int* __restrict__ ccur,
                                                    int* __restrict__ fcur,
                                                    int* __restrict__ fpairs) {
    __shared__ int lcnt[FPC];
    int t = threadIdx.x;
    int cb = blockIdx.x / NCHUNKB;
    int k  = blockIdx.x % NCHUNKB;
    int beg = cb * CCAP + k * CHUNKB;
    int end = cb * CCAP + ccur[cb];
    if (end > beg + CHUNKB) end = beg + CHUNKB;
    if (t < FPC) lcnt[t] = 0;
    __syncthreads();
    int pc[EPTB], pos[EPTB];
#pragma unroll
    for (int i = 0; i < EPTB; ++i) {
        int e = beg + i * 256 + t;
        if (e < end) {
            pc[i] = cpairs[e];
            pos[i] = atomicAdd(&lcnt[pc[i] >> (COLBITS + FSHIFT)], 1);
        } else pc[i] = -1;
    }
    __syncthreads();
    if (t < FPC) {
        int cc = lcnt[t];
        if (cc) {
            int fb = (cb << 6) + t;
            lcnt[t] = fb * CAPF + atomicAdd(&fcur[fb], cc);
        }
    }
    __syncthreads();
#pragma unroll
    for (int i = 0; i < EPTB; ++i) {
        if (pc[i] >= 0) {
            int fl = pc[i] >> (COLBITS + FSHIFT);
            int rl5 = (pc[i] >> COLBITS) & (FNODES - 1);
            fpairs[lcnt[fl] + pos[i]] = (rl5 << COLBITS) | (pc[i] & COLMASK);
        }
    }
}

// y[n] = bf16(dinv[n] * x[n] @ W^T); dinv from global deg (written out too).
__global__ __launch_bounds__(256) void xform_kernel(
        const float* __restrict__ x, const float* __restrict__ W,
        const int* __restrict__ deg, float* __restrict__ dinv,
        unsigned short* __restrict__ y) {
    __shared__ __align__(16) float XT[D * 68];   // XT[d*68 + n]
    __shared__ __align__(16) float WT[D * 68];   // WT[d*68 + j]
    __shared__ float dl[64];
    int t = threadIdx.x;
    int b = blockIdx.x;
    int nb0 = b << 6;
    for (int i = t; i < D * D; i += 256) {
        int j = i >> 6, d = i & 63;
        WT[d * 68 + j] = W[i];
    }
    if (t < 64) {
        int g = nb0 + t;
        float dv = 0.0f;
        if (g < N_NODES) {
            int dgv = deg[g];
            dv = (dgv > 0) ? rsqrtf((float)dgv) : 0.0f;
            dinv[g] = dv;
        }
        dl[t] = dv;
    }
    for (int i = t; i < 64 * D; i += 256) {
        int n = i >> 6, d = i & 63;
        int g = nb0 + n;
        XT[d * 68 + n] = (g < N_NODES) ? x[(size_t)g * D + d] : 0.0f;
    }
    __syncthreads();
    int tj = t & 15, tn = t >> 4;
    float4 a0 = {0,0,0,0}, a1 = {0,0,0,0}, a2 = {0,0,0,0}, a3 = {0,0,0,0};
#pragma unroll 8
    for (int d = 0; d < D; ++d) {
        float4 xv = *(const float4*)&XT[d * 68 + tn * 4];
        float4 wv = *(const float4*)&WT[d * 68 + tj * 4];
        a0.x = fmaf(xv.x, wv.x, a0.x); a0.y = fmaf(xv.x, wv.y, a0.y);
        a0.z = fmaf(xv.x, wv.z, a0.z); a0.w = fmaf(xv.x, wv.w, a0.w);
        a1.x = fmaf(xv.y, wv.x, a1.x); a1.y = fmaf(xv.y, wv.y, a1.y);
        a1.z = fmaf(xv.y, wv.z, a1.z); a1.w = fmaf(xv.y, wv.w, a1.w);
        a2.x = fmaf(xv.z, wv.x, a2.x); a2.y = fmaf(xv.z, wv.y, a2.y);
        a2.z = fmaf(xv.z, wv.z, a2.z); a2.w = fmaf(xv.z, wv.w, a2.w);
        a3.x = fmaf(xv.w, wv.x, a3.x); a3.y = fmaf(xv.w, wv.y, a3.y);
        a3.z = fmaf(xv.w, wv.z, a3.z); a3.w = fmaf(xv.w, wv.w, a3.w);
    }
    int jb = tj * 4;
#pragma unroll
    for (int s = 0; s < 4; ++s) {
        int g = nb0 + tn * 4 + s;
        if (g < N_NODES) {
            float scv = dl[tn * 4 + s];
            float4 a = (s == 0) ? a0 : (s == 1) ? a1 : (s == 2) ? a2 : a3;
            unsigned lo = f2bf(a.x * scv) | (f2bf(a.y * scv) << 16);
            unsigned hi = f2bf(a.z * scv) | (f2bf(a.w * scv) << 16);
            *(uint2*)(y + (size_t)g * D + jb) = make_uint2(lo, hi);
        }
    }
}

// Per fine bucket (32 nodes): LDS fp32 accumulate via ds_add_f32.
// Lane = (edge slot g 0..7) x (feat block q 0..7). One uint4 = 8 bf16 feats;
// 8 LDS float atomics per lane. No hist/scan/bin/shuffles. acc row stride 68
// (pad) spreads banks; epilogue reads are exactly 2-way (free).
__global__ __launch_bounds__(256) void mega_kernel(
        const int* __restrict__ fpairs, const int* __restrict__ fcur,
        const unsigned short* __restrict__ y, const float* __restrict__ dinv,
        const float* __restrict__ bias, float* __restrict__ out) {
    __shared__ float acc[FNODES][68];
    int t = threadIdx.x;
    int b = blockIdx.x;
    for (int i = t; i < FNODES * 68; i += 256) ((float*)acc)[i] = 0.0f;
    __syncthreads();
    int beg = b * CAPF;
    int cnt = fcur[b];
    int w = t >> 6;
    int lane = t & 63;
    int g = lane >> 3;   // edge slot
    int q = lane & 7;    // feat block
    for (int base = w * 8; base < cnt; base += 32) {
        int e = base + g;
        if (e < cnt) {
            int p = fpairs[beg + e];
            int rl = p >> COLBITS;
            int c = p & COLMASK;
            uint4 v = *(const uint4*)(y + (size_t)c * D + q * 8);
            float* a = &acc[rl][q * 8];
            atomicAdd(a + 0, __uint_as_float(v.x << 16));
            atomicAdd(a + 1, __uint_as_float(v.x & 0xffff0000u));
            atomicAdd(a + 2, __uint_as_float(v.y << 16));
            atomicAdd(a + 3, __uint_as_float(v.y & 0xffff0000u));
            atomicAdd(a + 4, __uint_as_float(v.z << 16));
            atomicAdd(a + 5, __uint_as_float(v.z & 0xffff0000u));
            atomicAdd(a + 6, __uint_as_float(v.w << 16));
            atomicAdd(a + 7, __uint_as_float(v.w & 0xffff0000u));
        }
    }
    __syncthreads();
    // epilogue: thread t -> node ln = t>>3, feats fq..fq+7
    int ln = t >> 3;
    int fq = (t & 7) * 8;
    int n = (b << FSHIFT) + ln;
    float dv = dinv[n];
    float4 b0 = *(const float4*)(bias + fq);
    float4 b1 = *(const float4*)(bias + fq + 4);
    const float* a = &acc[ln][fq];
    fvec4 r0, r1;
    r0.x = fmaxf(fmaf(dv, a[0], b0.x), 0.0f);
    r0.y = fmaxf(fmaf(dv, a[1], b0.y), 0.0f);
    r0.z = fmaxf(fmaf(dv, a[2], b0.z), 0.0f);
    r0.w = fmaxf(fmaf(dv, a[3], b0.w), 0.0f);
    r1.x = fmaxf(fmaf(dv, a[4], b1.x), 0.0f);
    r1.y = fmaxf(fmaf(dv, a[5], b1.y), 0.0f);
    r1.z = fmaxf(fmaf(dv, a[6], b1.z), 0.0f);
    r1.w = fmaxf(fmaf(dv, a[7], b1.w), 0.0f);
    __builtin_nontemporal_store(r0, (fvec4*)(out + (size_t)n * D + fq));
    __builtin_nontemporal_store(r1, (fvec4*)(out + (size_t)n * D + fq + 4));
}

extern "C" void kernel_launch(void* const* d_in, const int* in_sizes, int n_in,
                              void* d_out, int out_size, void* d_ws, size_t ws_size,
                              hipStream_t stream) {
    const float* x    = (const float*)d_in[0];
    const int*   eidx = (const int*)d_in[1];
    const float* W    = (const float*)d_in[2];
    const float* b    = (const float*)d_in[3];
    float* out = (float*)d_out;
    char* ws = (char*)d_ws;

    const int* row = eidx;
    const int* col = eidx + N_EDGES;

    int*   deg    = (int*)  (ws + DEG_OFF);
    int*   ccur   = (int*)  (ws + CCUR_OFF);
    int*   fcur   = (int*)  (ws + FCUR_OFF);
    float* dinv   = (float*)(ws + DINV_OFF);
    unsigned short* y = (unsigned short*)(ws + Y_OFF);
    int*   cpairs = (int*)  (ws + CPAIRS_OFF);
    int*   fpairs = (int*)  (ws + FPAIRS_OFF);

    hipMemsetAsync(ws, 0, INIT_BYTES, stream);
    scatA_kernel<<<NCHUNKA, 256, 0, stream>>>(row, col, deg, ccur, cpairs);
    scatB_kernel<<<NCB * NCHUNKB, 256, 0, stream>>>(cpairs, ccur, fcur, fpairs);
    xform_kernel<<<(N_NODES + 63) / 64, 256, 0, stream>>>(x, W, deg, dinv, y);
    mega_kernel<<<NFB, 256, 0, stream>>>(fpairs, fcur, y, dinv, b, out);
}

// Round 10
// 207.617 us; speedup vs baseline: 3.5986x; 3.5986x over previous
//
#include <hip/hip_runtime.h>

#define N_NODES 100000
#define N_EDGES 1600000
#define D 64

// fine buckets: 32 nodes, 100000/32 = 3125 exactly
#define FSHIFT 5
#define FNODES 32
#define NFB 3125
#define CAPF 768            // mean 512, sigma ~22.6 -> +11.3 sigma

// coarse buckets: 2048 nodes
#define CSHIFT 11
#define CNODES 2048
#define NCB 49
#define CCAP 36864          // mean 32768, +22 sigma
#define FPC 64

#define CHUNKA 4096
#define EPTA 16
#define NCHUNKA 391
#define CHUNKB 2048
#define EPTB 8
#define NCHUNKB 18          // CCAP / 2048

#define COLBITS 17
#define COLMASK 0x1FFFF

// ws layout (bytes)
#define CCUR_OFF   0           // int[49]   (counts, zero-init)
#define FCUR_OFF   256         // int[3125] (counts, zero-init)
#define INIT_BYTES 12756
#define DINV_OFF   16384       // float[100000]
#define Y_OFF      417792      // bf16[100000*64]
#define CPAIRS_OFF 13217792    // int[49*36864]
#define FPAIRS_OFF 20443136    // int[3125*768]

typedef float fvec4 __attribute__((ext_vector_type(4)));

__device__ __forceinline__ unsigned f2bf(float f) {
    unsigned bits = __float_as_uint(f);
    return (bits + 0x7FFFu + ((bits >> 16) & 1u)) >> 16;
}

// Pass A: bucket edges by row>>11 into 49 coarse regions.
// Wave-private LDS counters: atomic returns only contend within a wave.
__global__ __launch_bounds__(256) void scatA_kernel(const int* __restrict__ row,
                                                    const int* __restrict__ col,
                                                    int* __restrict__ ccur,
                                                    int* __restrict__ cpairs) {
    __shared__ int lcnt[4][52];
    __shared__ int wbase[4][52];
    int t = threadIdx.x;
    int w = t >> 6;
    int base = blockIdx.x * CHUNKA;
    for (int i = t; i < 4 * 52; i += 256) ((int*)lcnt)[i] = 0;
    __syncthreads();
    int r[EPTA], c[EPTA], pos[EPTA];
#pragma unroll
    for (int i = 0; i < EPTA; ++i) {
        int e = base + i * 256 + t;
        if (e < N_EDGES) {
            r[i] = row[e];
            c[i] = col[e];
            pos[i] = atomicAdd(&lcnt[w][r[i] >> CSHIFT], 1);
        } else r[i] = -1;
    }
    __syncthreads();
    if (t < NCB) {
        int c0 = lcnt[0][t], c1 = lcnt[1][t], c2 = lcnt[2][t], c3 = lcnt[3][t];
        int tot = c0 + c1 + c2 + c3;
        int g = t * CCAP;
        if (tot) g += atomicAdd(&ccur[t], tot);
        wbase[0][t] = g;
        wbase[1][t] = g + c0;
        wbase[2][t] = g + c0 + c1;
        wbase[3][t] = g + c0 + c1 + c2;
    }
    __syncthreads();
#pragma unroll
    for (int i = 0; i < EPTA; ++i) {
        if (r[i] >= 0) {
            int cb = r[i] >> CSHIFT;
            int rl = r[i] & (CNODES - 1);
            cpairs[wbase[w][cb] + pos[i]] = (rl << COLBITS) | c[i];
        }
    }
}

// Fused pass: blocks 0..48 compute dinv per coarse bucket (LDS hist over the
// bucket's cpairs region, non-atomic global write); blocks 49.. refine cpairs
// chunks into fine buckets (wave-private counters). Independent block roles.
__global__ __launch_bounds__(256) void scatB_dinv_kernel(
        const int* __restrict__ cpairs, const int* __restrict__ ccur,
        int* __restrict__ fcur, int* __restrict__ fpairs,
        float* __restrict__ dinv) {
    __shared__ int hist[CNODES];            // dinv role (8 KB)
    __shared__ int lcnt[4][FPC];            // scatB role
    __shared__ int wbase[4][FPC];
    int t = threadIdx.x;
    int blk = blockIdx.x;
    if (blk < NCB) {
        // ---- dinv role: histogram my coarse region ----
        int cb = blk;
        int beg = cb * CCAP;
        int end = beg + ccur[cb];
        for (int i = t; i < CNODES; i += 256) hist[i] = 0;
        __syncthreads();
        for (int k = beg + t; k < end; k += 256)
            atomicAdd(&hist[cpairs[k] >> COLBITS], 1);
        __syncthreads();
        for (int i = t; i < CNODES; i += 256) {
            int n = (cb << CSHIFT) + i;
            if (n < N_NODES) {
                int d = hist[i];
                dinv[n] = (d > 0) ? rsqrtf((float)d) : 0.0f;
            }
        }
        return;
    }
    // ---- scatB role ----
    int w = t >> 6;
    int bb = blk - NCB;
    int cb = bb / NCHUNKB;
    int k  = bb % NCHUNKB;
    int beg = cb * CCAP + k * CHUNKB;
    int end = cb * CCAP + ccur[cb];
    if (end > beg + CHUNKB) end = beg + CHUNKB;
    for (int i = t; i < 4 * FPC; i += 256) ((int*)lcnt)[i] = 0;
    __syncthreads();
    int pc[EPTB], pos[EPTB];
#pragma unroll
    for (int i = 0; i < EPTB; ++i) {
        int e = beg + i * 256 + t;
        if (e < end) {
            pc[i] = cpairs[e];
            pos[i] = atomicAdd(&lcnt[w][pc[i] >> (COLBITS + FSHIFT)], 1);
        } else pc[i] = -1;
    }
    __syncthreads();
    if (t < FPC) {
        int c0 = lcnt[0][t], c1 = lcnt[1][t], c2 = lcnt[2][t], c3 = lcnt[3][t];
        int tot = c0 + c1 + c2 + c3;
        int fb = (cb << 6) + t;
        int g = fb * CAPF;
        if (tot) g += atomicAdd(&fcur[fb], tot);
        wbase[0][t] = g;
        wbase[1][t] = g + c0;
        wbase[2][t] = g + c0 + c1;
        wbase[3][t] = g + c0 + c1 + c2;
    }
    __syncthreads();
#pragma unroll
    for (int i = 0; i < EPTB; ++i) {
        if (pc[i] >= 0) {
            int fl = pc[i] >> (COLBITS + FSHIFT);
            int rl5 = (pc[i] >> COLBITS) & (FNODES - 1);
            fpairs[wbase[w][fl] + pos[i]] = (rl5 << COLBITS) | (pc[i] & COLMASK);
        }
    }
}

// y[n] = bf16(dinv[n] * x[n] @ W^T); reads precomputed dinv.
__global__ __launch_bounds__(256) void xform_kernel(
        const float* __restrict__ x, const float* __restrict__ W,
        const float* __restrict__ dinv, unsigned short* __restrict__ y) {
    __shared__ __align__(16) float XT[D * 68];   // XT[d*68 + n]
    __shared__ __align__(16) float WT[D * 68];   // WT[d*68 + j]
    __shared__ float dl[64];
    int t = threadIdx.x;
    int b = blockIdx.x;
    int nb0 = b << 6;
    for (int i = t; i < D * D; i += 256) {
        int j = i >> 6, d = i & 63;
        WT[d * 68 + j] = W[i];
    }
    if (t < 64) {
        int g = nb0 + t;
        dl[t] = (g < N_NODES) ? dinv[g] : 0.0f;
    }
    for (int i = t; i < 64 * D; i += 256) {
        int n = i >> 6, d = i & 63;
        int g = nb0 + n;
        XT[d * 68 + n] = (g < N_NODES) ? x[(size_t)g * D + d] : 0.0f;
    }
    __syncthreads();
    int tj = t & 15, tn = t >> 4;
    float4 a0 = {0,0,0,0}, a1 = {0,0,0,0}, a2 = {0,0,0,0}, a3 = {0,0,0,0};
#pragma unroll 8
    for (int d = 0; d < D; ++d) {
        float4 xv = *(const float4*)&XT[d * 68 + tn * 4];
        float4 wv = *(const float4*)&WT[d * 68 + tj * 4];
        a0.x = fmaf(xv.x, wv.x, a0.x); a0.y = fmaf(xv.x, wv.y, a0.y);
        a0.z = fmaf(xv.x, wv.z, a0.z); a0.w = fmaf(xv.x, wv.w, a0.w);
        a1.x = fmaf(xv.y, wv.x, a1.x); a1.y = fmaf(xv.y, wv.y, a1.y);
        a1.z = fmaf(xv.y, wv.z, a1.z); a1.w = fmaf(xv.y, wv.w, a1.w);
        a2.x = fmaf(xv.z, wv.x, a2.x); a2.y = fmaf(xv.z, wv.y, a2.y);
        a2.z = fmaf(xv.z, wv.z, a2.z); a2.w = fmaf(xv.z, wv.w, a2.w);
        a3.x = fmaf(xv.w, wv.x, a3.x); a3.y = fmaf(xv.w, wv.y, a3.y);
        a3.z = fmaf(xv.w, wv.z, a3.z); a3.w = fmaf(xv.w, wv.w, a3.w);
    }
    int jb = tj * 4;
#pragma unroll
    for (int s = 0; s < 4; ++s) {
        int g = nb0 + tn * 4 + s;
        if (g < N_NODES) {
            float scv = dl[tn * 4 + s];
            float4 a = (s == 0) ? a0 : (s == 1) ? a1 : (s == 2) ? a2 : a3;
            unsigned lo = f2bf(a.x * scv) | (f2bf(a.y * scv) << 16);
            unsigned hi = f2bf(a.z * scv) | (f2bf(a.w * scv) << 16);
            *(uint2*)(y + (size_t)g * D + jb) = make_uint2(lo, hi);
        }
    }
}

// Per fine bucket (32 nodes): LDS hist -> scan -> fine-bin -> wide gather
// (R7-proven). lane=(g<<3)|q: g edge slot, q feature block (8 bf16 = 16B).
__global__ __launch_bounds__(256) void mega_kernel(
        const int* __restrict__ fpairs, const int* __restrict__ fcur,
        const unsigned short* __restrict__ y,
        const float* __restrict__ bias, float* __restrict__ out) {
    __shared__ int hist[FNODES];
    __shared__ int sc[FNODES];
    __shared__ int lrptr[FNODES + 1];
    __shared__ int lcur[FNODES];
    __shared__ float dl[FNODES];
    __shared__ int lds_scol[CAPF];
    int t = threadIdx.x;
    int b = blockIdx.x;
    int beg = b * CAPF;
    int cnt = fcur[b];
    if (t < FNODES) hist[t] = 0;
    __syncthreads();
    for (int k = t; k < cnt; k += 256)
        atomicAdd(&hist[fpairs[beg + k] >> COLBITS], 1);
    __syncthreads();
    if (t < FNODES) sc[t] = hist[t];
    __syncthreads();
    for (int off = 1; off < FNODES; off <<= 1) {
        int v = (t < FNODES && t >= off) ? sc[t - off] : 0;
        __syncthreads();
        if (t < FNODES) sc[t] += v;
        __syncthreads();
    }
    if (t < FNODES) {
        lrptr[t + 1] = sc[t];
        lcur[t] = sc[t] - hist[t];
        dl[t] = (hist[t] > 0) ? rsqrtf((float)hist[t]) : 0.0f;
    }
    if (t == 0) lrptr[0] = 0;
    __syncthreads();
    for (int k = t; k < cnt; k += 256) {
        int p = fpairs[beg + k];
        int pos = atomicAdd(&lcur[p >> COLBITS], 1);
        lds_scol[pos] = p & COLMASK;
    }
    __syncthreads();
    int wave = t >> 6;
    int lane = t & 63;
    int g = lane >> 3;     // edge slot 0..7
    int q = lane & 7;      // feature block
    float bj[8];
    {
        float4 b0 = *(const float4*)(bias + q * 8);
        float4 b1 = *(const float4*)(bias + q * 8 + 4);
        bj[0] = b0.x; bj[1] = b0.y; bj[2] = b0.z; bj[3] = b0.w;
        bj[4] = b1.x; bj[5] = b1.y; bj[6] = b1.z; bj[7] = b1.w;
    }
    for (int ln = wave; ln < FNODES; ln += 4) {
        int s = lrptr[ln], e2 = lrptr[ln + 1];
        float a[8];
#pragma unroll
        for (int i = 0; i < 8; ++i) a[i] = 0.0f;
        for (int k = s; k < e2; k += 32) {
#pragma unroll
            for (int u = 0; u < 4; ++u) {
                int e = k + u * 8 + g;
                if (e < e2) {
                    int c = lds_scol[e];
                    uint4 v = *(const uint4*)(y + (size_t)c * D + q * 8);
                    a[0] += __uint_as_float(v.x << 16);
                    a[1] += __uint_as_float(v.x & 0xffff0000u);
                    a[2] += __uint_as_float(v.y << 16);
                    a[3] += __uint_as_float(v.y & 0xffff0000u);
                    a[4] += __uint_as_float(v.z << 16);
                    a[5] += __uint_as_float(v.z & 0xffff0000u);
                    a[6] += __uint_as_float(v.w << 16);
                    a[7] += __uint_as_float(v.w & 0xffff0000u);
                }
            }
        }
#pragma unroll
        for (int m = 8; m <= 32; m <<= 1) {
#pragma unroll
            for (int i = 0; i < 8; ++i)
                a[i] += __shfl_xor(a[i], m);
        }
        float dv = dl[ln];
        int n = (b << FSHIFT) + ln;
        if (g < 2) {
            int o = g * 4;
            fvec4 r;
            r.x = fmaxf(fmaf(dv, a[o + 0], bj[o + 0]), 0.0f);
            r.y = fmaxf(fmaf(dv, a[o + 1], bj[o + 1]), 0.0f);
            r.z = fmaxf(fmaf(dv, a[o + 2], bj[o + 2]), 0.0f);
            r.w = fmaxf(fmaf(dv, a[o + 3], bj[o + 3]), 0.0f);
            __builtin_nontemporal_store(r, (fvec4*)(out + (size_t)n * D + q * 8 + o));
        }
    }
}

extern "C" void kernel_launch(void* const* d_in, const int* in_sizes, int n_in,
                              void* d_out, int out_size, void* d_ws, size_t ws_size,
                              hipStream_t stream) {
    const float* x    = (const float*)d_in[0];
    const int*   eidx = (const int*)d_in[1];
    const float* W    = (const float*)d_in[2];
    const float* b    = (const float*)d_in[3];
    float* out = (float*)d_out;
    char* ws = (char*)d_ws;

    const int* row = eidx;
    const int* col = eidx + N_EDGES;

    int*   ccur   = (int*)  (ws + CCUR_OFF);
    int*   fcur   = (int*)  (ws + FCUR_OFF);
    float* dinv   = (float*)(ws + DINV_OFF);
    unsigned short* y = (unsigned short*)(ws + Y_OFF);
    int*   cpairs = (int*)  (ws + CPAIRS_OFF);
    int*   fpairs = (int*)  (ws + FPAIRS_OFF);

    hipMemsetAsync(ws, 0, INIT_BYTES, stream);
    scatA_kernel<<<NCHUNKA, 256, 0, stream>>>(row, col, ccur, cpairs);
    scatB_dinv_kernel<<<NCB + NCB * NCHUNKB, 256, 0, stream>>>(cpairs, ccur, fcur, fpairs, dinv);
    xform_kernel<<<(N_NODES + 63) / 64, 256, 0, stream>>>(x, W, dinv, y);
    mega_kernel<<<NFB, 256, 0, stream>>>(fpairs, fcur, y, b, out);
}

// Round 11
// 186.344 us; speedup vs baseline: 4.0094x; 1.1142x over previous
//
#include <hip/hip_runtime.h>

#define N_NODES 100000
#define N_EDGES 1600000
#define D 64

// fine buckets: 32 nodes, 100000/32 = 3125 exactly
#define FSHIFT 5
#define FNODES 32
#define NFB 3125
#define CAPF 768            // mean 512, sigma ~22.6 -> +11.3 sigma

// coarse buckets: 2048 nodes
#define CSHIFT 11
#define CNODES 2048
#define NCB 49
#define CCAP 36864          // mean 32768, +22 sigma
#define FPC 64

#define CHUNK 4096
#define EPT 16
#define NCHUNKA 391         // ceil(1600000/4096)
#define NCHUNKB 9           // CCAP / 4096
#define NSB (NCB * NCHUNKB) // 441 scatB blocks
#define NXF 1563            // xform blocks (1563*64 = 100032)

#define COLBITS 17
#define COLMASK 0x1FFFF

// ws layout (bytes)
#define CCUR_OFF   0           // int[49]   counts (zero-init)
#define FCUR_OFF   256         // int[3125] counts (zero-init)
#define INIT_BYTES 12756
#define DINV_OFF   16384       // float[100000]
#define Y_OFF      417792      // bf16[100000*64]
#define CPAIRS_OFF 13217792    // int[49*36864]
#define FPAIRS_OFF 20443136    // int[3125*768]

typedef float fvec4 __attribute__((ext_vector_type(4)));

__device__ __forceinline__ unsigned f2bf(float f) {
    unsigned bits = __float_as_uint(f);
    return (bits + 0x7FFFu + ((bits >> 16) & 1u)) >> 16;
}

// Pass A (R7-exact): bucket edges by row>>11 into 49 coarse regions.
// Block-shared counters -> ~84-edge (336 B) append runs per bucket.
__global__ __launch_bounds__(256) void scatA_kernel(const int* __restrict__ row,
                                                    const int* __restrict__ col,
                                                    int* __restrict__ ccur,
                                                    int* __restrict__ cpairs) {
    __shared__ int lcnt[NCB];
    int t = threadIdx.x;
    int base = blockIdx.x * CHUNK;
    if (t < NCB) lcnt[t] = 0;
    __syncthreads();
    int r[EPT], c[EPT], pos[EPT];
#pragma unroll
    for (int i = 0; i < EPT; ++i) {
        int e = base + i * 256 + t;
        if (e < N_EDGES) {
            r[i] = row[e];
            c[i] = col[e];
            pos[i] = atomicAdd(&lcnt[r[i] >> CSHIFT], 1);
        } else r[i] = -1;
    }
    __syncthreads();
    if (t < NCB) {
        int cc = lcnt[t];
        if (cc) lcnt[t] = t * CCAP + atomicAdd(&ccur[t], cc);
    }
    __syncthreads();
#pragma unroll
    for (int i = 0; i < EPT; ++i) {
        if (r[i] >= 0) {
            int cb = r[i] >> CSHIFT;
            int rl = r[i] & (CNODES - 1);
            cpairs[lcnt[cb] + pos[i]] = (rl << COLBITS) | c[i];
        }
    }
}

// dinv per coarse bucket: 2048-wide LDS hist over my cpairs region
// (18-way avg collisions), non-atomic global write. 49 blocks x 1024 thr.
__global__ __launch_bounds__(1024) void dinv_kernel(const int* __restrict__ cpairs,
                                                    const int* __restrict__ ccur,
                                                    float* __restrict__ dinv) {
    __shared__ int hist[CNODES];
    int t = threadIdx.x;
    int cb = blockIdx.x;
    for (int i = t; i < CNODES; i += 1024) hist[i] = 0;
    __syncthreads();
    int beg = cb * CCAP;
    int end = beg + ccur[cb];
    for (int k = beg + t; k < end; k += 1024)
        atomicAdd(&hist[cpairs[k] >> COLBITS], 1);
    __syncthreads();
    for (int i = t; i < CNODES; i += 1024) {
        int n = (cb << CSHIFT) + i;
        if (n < N_NODES) {
            int d = hist[i];
            dinv[n] = (d > 0) ? rsqrtf((float)d) : 0.0f;
        }
    }
}

// Fused dispatch: blocks [0,441) = scatB role (refine cpairs chunk into 64
// fine buckets, R7-exact); blocks [441,441+1563) = xform role
// (y[n] = bf16(dinv[n] * x[n] @ W^T), 4x4 register tiles).
// scatB blocks first: their latency chains hide under xform's FMA stream.
__global__ __launch_bounds__(256) void sbxf_kernel(
        const int* __restrict__ cpairs, const int* __restrict__ ccur,
        int* __restrict__ fcur, int* __restrict__ fpairs,
        const float* __restrict__ x, const float* __restrict__ W,
        const float* __restrict__ dinv, unsigned short* __restrict__ y) {
    __shared__ __align__(16) float smem[2 * 64 * 68 + 64];   // 35 KB union
    int t = threadIdx.x;
    int blk = blockIdx.x;
    if (blk < NSB) {
        // ---- scatB role ----
        int* lcnt = (int*)smem;
        int cb = blk / NCHUNKB;
        int k  = blk % NCHUNKB;
        int beg = cb * CCAP + k * CHUNK;
        int end = cb * CCAP + ccur[cb];
        if (end > beg + CHUNK) end = beg + CHUNK;
        if (t < FPC) lcnt[t] = 0;
        __syncthreads();
        int pc[EPT], pos[EPT];
#pragma unroll
        for (int i = 0; i < EPT; ++i) {
            int e = beg + i * 256 + t;
            if (e < end) {
                pc[i] = cpairs[e];
                pos[i] = atomicAdd(&lcnt[pc[i] >> (COLBITS + FSHIFT)], 1);
            } else pc[i] = -1;
        }
        __syncthreads();
        if (t < FPC) {
            int cc = lcnt[t];
            if (cc) {
                int fb = (cb << 6) + t;
                lcnt[t] = fb * CAPF + atomicAdd(&fcur[fb], cc);
            }
        }
        __syncthreads();
#pragma unroll
        for (int i = 0; i < EPT; ++i) {
            if (pc[i] >= 0) {
                int fl = pc[i] >> (COLBITS + FSHIFT);
                int rl5 = (pc[i] >> COLBITS) & (FNODES - 1);
                fpairs[lcnt[fl] + pos[i]] = (rl5 << COLBITS) | (pc[i] & COLMASK);
            }
        }
        return;
    }
    // ---- xform role ----
    float* XT = smem;                 // XT[d*68 + n]
    float* WT = smem + 64 * 68;      // WT[d*68 + j]
    float* dl = smem + 2 * 64 * 68;  // [64]
    int b = blk - NSB;
    int nb0 = b << 6;
    for (int i = t; i < D * D; i += 256) {
        int j = i >> 6, d = i & 63;
        WT[d * 68 + j] = W[i];
    }
    if (t < 64) {
        int g = nb0 + t;
        dl[t] = (g < N_NODES) ? dinv[g] : 0.0f;
    }
    for (int i = t; i < 64 * D; i += 256) {
        int n = i >> 6, d = i & 63;
        int g = nb0 + n;
        XT[d * 68 + n] = (g < N_NODES) ? x[(size_t)g * D + d] : 0.0f;
    }
    __syncthreads();
    int tj = t & 15, tn = t >> 4;
    float4 a0 = {0,0,0,0}, a1 = {0,0,0,0}, a2 = {0,0,0,0}, a3 = {0,0,0,0};
#pragma unroll 8
    for (int d = 0; d < D; ++d) {
        float4 xv = *(const float4*)&XT[d * 68 + tn * 4];
        float4 wv = *(const float4*)&WT[d * 68 + tj * 4];
        a0.x = fmaf(xv.x, wv.x, a0.x); a0.y = fmaf(xv.x, wv.y, a0.y);
        a0.z = fmaf(xv.x, wv.z, a0.z); a0.w = fmaf(xv.x, wv.w, a0.w);
        a1.x = fmaf(xv.y, wv.x, a1.x); a1.y = fmaf(xv.y, wv.y, a1.y);
        a1.z = fmaf(xv.y, wv.z, a1.z); a1.w = fmaf(xv.y, wv.w, a1.w);
        a2.x = fmaf(xv.z, wv.x, a2.x); a2.y = fmaf(xv.z, wv.y, a2.y);
        a2.z = fmaf(xv.z, wv.z, a2.z); a2.w = fmaf(xv.z, wv.w, a2.w);
        a3.x = fmaf(xv.w, wv.x, a3.x); a3.y = fmaf(xv.w, wv.y, a3.y);
        a3.z = fmaf(xv.w, wv.z, a3.z); a3.w = fmaf(xv.w, wv.w, a3.w);
    }
    int jb = tj * 4;
#pragma unroll
    for (int s = 0; s < 4; ++s) {
        int g = nb0 + tn * 4 + s;
        if (g < N_NODES) {
            float scv = dl[tn * 4 + s];
            float4 a = (s == 0) ? a0 : (s == 1) ? a1 : (s == 2) ? a2 : a3;
            unsigned lo = f2bf(a.x * scv) | (f2bf(a.y * scv) << 16);
            unsigned hi = f2bf(a.z * scv) | (f2bf(a.w * scv) << 16);
            *(uint2*)(y + (size_t)g * D + jb) = make_uint2(lo, hi);
        }
    }
}

// Per fine bucket (32 nodes): LDS hist -> scan -> fine-bin -> wide gather.
// R7-proven, byte-identical. lane=(g<<3)|q: g edge slot, q feature block.
__global__ __launch_bounds__(256) void mega_kernel(
        const int* __restrict__ fpairs, const int* __restrict__ fcur,
        const unsigned short* __restrict__ y,
        const float* __restrict__ bias, float* __restrict__ out) {
    __shared__ int hist[FNODES];
    __shared__ int sc[FNODES];
    __shared__ int lrptr[FNODES + 1];
    __shared__ int lcur[FNODES];
    __shared__ float dl[FNODES];
    __shared__ int lds_scol[CAPF];
    int t = threadIdx.x;
    int b = blockIdx.x;
    int beg = b * CAPF;
    int cnt = fcur[b];
    if (t < FNODES) hist[t] = 0;
    __syncthreads();
    for (int k = t; k < cnt; k += 256)
        atomicAdd(&hist[fpairs[beg + k] >> COLBITS], 1);
    __syncthreads();
    if (t < FNODES) sc[t] = hist[t];
    __syncthreads();
    for (int off = 1; off < FNODES; off <<= 1) {
        int v = (t < FNODES && t >= off) ? sc[t - off] : 0;
        __syncthreads();
        if (t < FNODES) sc[t] += v;
        __syncthreads();
    }
    if (t < FNODES) {
        lrptr[t + 1] = sc[t];
        lcur[t] = sc[t] - hist[t];
        dl[t] = (hist[t] > 0) ? rsqrtf((float)hist[t]) : 0.0f;
    }
    if (t == 0) lrptr[0] = 0;
    __syncthreads();
    for (int k = t; k < cnt; k += 256) {
        int p = fpairs[beg + k];
        int pos = atomicAdd(&lcur[p >> COLBITS], 1);
        lds_scol[pos] = p & COLMASK;
    }
    __syncthreads();
    int wave = t >> 6;
    int lane = t & 63;
    int g = lane >> 3;     // edge slot 0..7
    int q = lane & 7;      // feature block
    float bj[8];
    {
        float4 b0 = *(const float4*)(bias + q * 8);
        float4 b1 = *(const float4*)(bias + q * 8 + 4);
        bj[0] = b0.x; bj[1] = b0.y; bj[2] = b0.z; bj[3] = b0.w;
        bj[4] = b1.x; bj[5] = b1.y; bj[6] = b1.z; bj[7] = b1.w;
    }
    for (int ln = wave; ln < FNODES; ln += 4) {
        int s = lrptr[ln], e2 = lrptr[ln + 1];
        float a[8];
#pragma unroll
        for (int i = 0; i < 8; ++i) a[i] = 0.0f;
        for (int k = s; k < e2; k += 32) {
#pragma unroll
            for (int u = 0; u < 4; ++u) {
                int e = k + u * 8 + g;
                if (e < e2) {
                    int c = lds_scol[e];
                    uint4 v = *(const uint4*)(y + (size_t)c * D + q * 8);
                    a[0] += __uint_as_float(v.x << 16);
                    a[1] += __uint_as_float(v.x & 0xffff0000u);
                    a[2] += __uint_as_float(v.y << 16);
                    a[3] += __uint_as_float(v.y & 0xffff0000u);
                    a[4] += __uint_as_float(v.z << 16);
                    a[5] += __uint_as_float(v.z & 0xffff0000u);
                    a[6] += __uint_as_float(v.w << 16);
                    a[7] += __uint_as_float(v.w & 0xffff0000u);
                }
            }
        }
#pragma unroll
        for (int m = 8; m <= 32; m <<= 1) {
#pragma unroll
            for (int i = 0; i < 8; ++i)
                a[i] += __shfl_xor(a[i], m);
        }
        float dv = dl[ln];
        int n = (b << FSHIFT) + ln;
        if (g < 2) {
            int o = g * 4;
            fvec4 r;
            r.x = fmaxf(fmaf(dv, a[o + 0], bj[o + 0]), 0.0f);
            r.y = fmaxf(fmaf(dv, a[o + 1], bj[o + 1]), 0.0f);
            r.z = fmaxf(fmaf(dv, a[o + 2], bj[o + 2]), 0.0f);
            r.w = fmaxf(fmaf(dv, a[o + 3], bj[o + 3]), 0.0f);
            __builtin_nontemporal_store(r, (fvec4*)(out + (size_t)n * D + q * 8 + o));
        }
    }
}

extern "C" void kernel_launch(void* const* d_in, const int* in_sizes, int n_in,
                              void* d_out, int out_size, void* d_ws, size_t ws_size,
                              hipStream_t stream) {
    const float* x    = (const float*)d_in[0];
    const int*   eidx = (const int*)d_in[1];
    const float* W    = (const float*)d_in[2];
    const float* b    = (const float*)d_in[3];
    float* out = (float*)d_out;
    char* ws = (char*)d_ws;

    const int* row = eidx;
    const int* col = eidx + N_EDGES;

    int*   ccur   = (int*)  (ws + CCUR_OFF);
    int*   fcur   = (int*)  (ws + FCUR_OFF);
    float* dinv   = (float*)(ws + DINV_OFF);
    unsigned short* y = (unsigned short*)(ws + Y_OFF);
    int*   cpairs = (int*)  (ws + CPAIRS_OFF);
    int*   fpairs = (int*)  (ws + FPAIRS_OFF);

    hipMemsetAsync(ws, 0, INIT_BYTES, stream);
    scatA_kernel<<<NCHUNKA, 256, 0, stream>>>(row, col, ccur, cpairs);
    dinv_kernel<<<NCB, 1024, 0, stream>>>(cpairs, ccur, dinv);
    sbxf_kernel<<<NSB + NXF, 256, 0, stream>>>(cpairs, ccur, fcur, fpairs, x, W, dinv, y);
    mega_kernel<<<NFB, 256, 0, stream>>>(fpairs, fcur, y, b, out);
}